// Round 14
// baseline (212.825 us; speedup 1.0000x reference)
//
#include <hip/hip_runtime.h>
#include <cmath>

#define HW 3136          // 56*56
#define NF 64            // BB*LL frames
#define NBLK2 448        // NF * 7 row-tiles (conv blocks, 8 rows each)
#define YROWS 29         // Hermitian: rows 0..28 of spatial DFT stored
#define YPX 1624         // 29*56

typedef __attribute__((ext_vector_type(8))) short short8;
typedef __attribute__((ext_vector_type(4))) float float4a;

__device__ __forceinline__ unsigned short f2bf(float f) {
    unsigned int u = __float_as_uint(f);
    u += 0x7fffu + ((u >> 16) & 1u);   // RNE
    return (unsigned short)(u >> 16);
}
__device__ __forceinline__ float bf2f(unsigned short u) {
    return __uint_as_float(((unsigned int)u) << 16);
}
// LDS channel-group hash: spreads both read-side (consecutive lc) and
// write-side (stride-4 lc) accesses across all 8 16B slots.
__device__ __forceinline__ int lchash(int lc) {
    return (lc ^ (lc >> 2)) & 7;
}

// ---------------------------------------------------------------------------
// Kernel 0: pack DFT matrices + repack conv_w.
//  blocks 0..63   : Ffix (stage-2 B operand), k-slots interleaved:
//                   slot 2h = col-Re, 2h+1 = col-Im.
//                   p=0 -> [Fr | -Fi], p=1 -> [Fi | Fr].
//  blocks 64..207 : Wp[kk][o][i] bf16 from conv_w[o][i][kk].
//  blocks 208..223: Fs1 (stage-1 A operand): M-stack rows 0..28 = Fr rows,
//                   rows 32..60 = Fi rows, pads zero. K = 0..55 pad 64.
// ---------------------------------------------------------------------------
__global__ __launch_bounds__(256)
void pack_kernel(const float* __restrict__ cw,
                 unsigned short* __restrict__ Ffix,
                 unsigned short* __restrict__ Wp,
                 unsigned short* __restrict__ Fs1) {
    if (blockIdx.x < 64) {
        int idx = blockIdx.x * 256 + threadIdx.x;    // 16384
        int j    = idx & 7;
        int lane = (idx >> 3) & 63;
        int ks   = (idx >> 9) & 3;
        int t    = (idx >> 11) & 3;
        int p    = (idx >> 13) & 1;
        int mn = t * 16 + (lane & 15);
        int k  = ks * 32 + (lane >> 4) * 8 + j;      // interleaved slot
        float val = 0.f;
        if (mn < 56 && k < 112) {
            int h = k >> 1;
            int prod = (mn * h) % 56;
            float ang = -6.2831853071795864f * (float)prod / 56.0f;
            float cr = cosf(ang);                    // Fr
            float ci = sinf(ang);                    // Fi
            if (p == 0) val = (k & 1) ? -ci : cr;    // [Fr | -Fi]
            else        val = (k & 1) ?  cr : ci;    // [Fi |  Fr]
        }
        Ffix[idx] = f2bf(val);
    } else if (blockIdx.x < 208) {
        int idx = (blockIdx.x - 64) * 256 + threadIdx.x;
        if (idx < 36864) {
            int i  = idx & 63;
            int o  = (idx >> 6) & 63;
            int kk = idx >> 12;
            Wp[idx] = f2bf(cw[(o * 64 + i) * 9 + kk]);
        }
    } else {
        int idx = (blockIdx.x - 208) * 256 + threadIdx.x;  // 4096
        int j  = idx & 7;
        int ln = (idx >> 3) & 63;
        int ks = (idx >> 9) & 1;
        int mt = (idx >> 10) & 3;
        int m = mt * 16 + (ln & 15);
        int k = ks * 32 + (ln >> 4) * 8 + j;
        float val = 0.f;
        if (k < 56) {
            if (m < 29) {                            // Fr row m
                int prod = (m * k) % 56;
                val = cosf(-6.2831853071795864f * (float)prod / 56.0f);
            } else if (m >= 32 && m < 61) {          // Fi row m-32
                int mm = m - 32;
                int prod = (mm * k) % 56;
                val = sinf(-6.2831853071795864f * (float)prod / 56.0f);
            }
        }
        Fs1[idx] = f2bf(val);
    }
}

// ---------------------------------------------------------------------------
// Kernel 1a: per-plane spatial 2D DFT (rows 0..28 via Hermitian symmetry).
// XCD-aligned decode: l = bid>>9, bc = bid&511 -> all 8 l-planes of a (b,c)
// land on XCD bc%8 (shared x neighborhood + Y[bc] written XCD-locally).
// ---------------------------------------------------------------------------
__global__ __launch_bounds__(256)
void dft2d_kernel(const float* __restrict__ x,
                  const unsigned short* __restrict__ Fs1,
                  const unsigned short* __restrict__ Ffix,
                  unsigned short* __restrict__ Y) {
    const int bid = blockIdx.x;
    const int l  = bid >> 9;             // 0..7
    const int bc = bid & 511;            // b*64 + c ; XCD = bc%8
    const int c  = bc & 63;
    const int b  = bc >> 6;
    const int tid  = threadIdx.x;
    const int lane = tid & 63;
    const int wv   = tid >> 6;           // 0..3
    const int n    = lane & 15;
    const int q    = lane >> 4;

    __shared__ unsigned short xT[64 * 68];   // [w][h] stride 68, 8704 B
    __shared__ unsigned short P[32 * 136];   // [r][slot] stride 136, 8704 B

    // zero ONLY xT pad regions (disjoint from staged area)
    for (int t = tid; t < 656; t += 256) {
        if (t < 384) ((unsigned int*)xT)[(t / 6) * 34 + 28 + (t % 6)] = 0u;
        else         ((unsigned int*)xT)[56 * 34 + (t - 384)] = 0u;
    }
    // stage x plane -> xT (transposed, bf16)
    const float* xp = x + ((size_t)((b * 8 + l) * 64 + c)) * HW;
    for (int t = tid; t < 784; t += 256) {
        int h = t / 14, w4 = t - h * 14;
        float4 v = *(const float4*)(xp + h * 56 + w4 * 4);
        xT[(w4 * 4 + 0) * 68 + h] = f2bf(v.x);
        xT[(w4 * 4 + 1) * 68 + h] = f2bf(v.y);
        xT[(w4 * 4 + 2) * 68 + h] = f2bf(v.z);
        xT[(w4 * 4 + 3) * 68 + h] = f2bf(v.w);
    }
    __syncthreads();

    // ---- stage 1: wave wv owns m-tile wv. out P[m][w], K = h (56 pad 64) ----
    {
        float4a acc[4];
        #pragma unroll
        for (int nt = 0; nt < 4; ++nt) acc[nt] = (float4a){0.f, 0.f, 0.f, 0.f};
        #pragma unroll
        for (int ks = 0; ks < 2; ++ks) {
            short8 afr = *(const short8*)(Fs1 + ((size_t)((wv * 2 + ks) * 64 + lane)) * 8);
            #pragma unroll
            for (int nt = 0; nt < 4; ++nt) {
                short8 bfr = *(const short8*)(xT + (nt * 16 + n) * 68 + ks * 32 + q * 8);
                acc[nt] = __builtin_amdgcn_mfma_f32_16x16x32_bf16(afr, bfr, acc[nt], 0, 0, 0);
            }
        }
        #pragma unroll
        for (int nt = 0; nt < 4; ++nt)
            #pragma unroll
            for (int r = 0; r < 4; ++r) {
                int m = wv * 16 + q * 4 + r;
                P[(m & 31) * 136 + 2 * (nt * 16 + n) + (m >> 5)] = f2bf(acc[nt][r]);
            }
    }
    __syncthreads();

    // ---- stage 2: wave wv: p = wv>>1 (re/im), ch = wv&1 (col half) ----
    {
        const int p  = wv >> 1;
        const int ch = wv & 1;
        short8 afr[2][4];
        #pragma unroll
        for (int mt = 0; mt < 2; ++mt)
            #pragma unroll
            for (int ks = 0; ks < 4; ++ks)
                afr[mt][ks] = *(const short8*)(P + (mt * 16 + n) * 136 + ks * 32 + q * 8);
        float4a acc[2][2];
        #pragma unroll
        for (int mt = 0; mt < 2; ++mt)
            #pragma unroll
            for (int u = 0; u < 2; ++u) acc[mt][u] = (float4a){0.f, 0.f, 0.f, 0.f};
        #pragma unroll
        for (int ks = 0; ks < 4; ++ks)
            #pragma unroll
            for (int u = 0; u < 2; ++u) {
                int nt = ch * 2 + u;
                short8 bfr = *(const short8*)(Ffix + ((size_t)(((p * 4 + nt) * 4 + ks) * 64 + lane)) * 8);
                #pragma unroll
                for (int mt = 0; mt < 2; ++mt)
                    acc[mt][u] = __builtin_amdgcn_mfma_f32_16x16x32_bf16(afr[mt][ks], bfr, acc[mt][u], 0, 0, 0);
            }
        unsigned short* Yo = Y + ((size_t)(bc * 8 + l) * 2 + p) * YPX;
        #pragma unroll
        for (int mt = 0; mt < 2; ++mt)
            #pragma unroll
            for (int u = 0; u < 2; ++u)
                #pragma unroll
                for (int r = 0; r < 4; ++r) {
                    int row = mt * 16 + q * 4 + r;
                    int col = (ch * 2 + u) * 16 + n;
                    if (row < YROWS && col < 56)
                        Yo[row * 56 + col] = f2bf(acc[mt][u][r]);
                }
    }
}

// ---------------------------------------------------------------------------
// Kernel 1b: temporal combine + magnitude + weighted pooling.
// Split 2x per (b,c); XCD-aligned decode half = bid>>9, bc = bid&511 so this
// block runs on XCD bc%8 — the SAME XCD whose L2 holds Y[bc] (3.3 MB/XCD of
// Y fits the 4 MB per-XCD L2). mg stored bf16 (26 KB LDS), 4 blocks/CU.
// ---------------------------------------------------------------------------
__global__ __launch_bounds__(256)
void combine_kernel(const float* __restrict__ x,
                    const unsigned short* __restrict__ Y,
                    float* __restrict__ poolA, float* __restrict__ poolB) {
    const int bid = blockIdx.x;
    const int half = bid >> 9;           // 0 or 1
    const int bc = bid & 511;            // b*64 + c ; XCD = bc%8
    const int c  = bc & 63;
    const int b  = bc >> 6;
    const int tid  = threadIdx.x;
    const int lane = tid & 63;
    const int wv   = tid >> 6;

    __shared__ unsigned short mgus[8 * YPX];   // 25984 B (bf16 magnitudes)
    __shared__ float red[4][16];

    const float SQH = 0.70710678118654752f;
    // w8[k] = e^{-2*pi*i*k/8}: cr = cos, ci = -sin
    const float c8[8] = {1.f,  SQH, 0.f, -SQH, -1.f, -SQH, 0.f,  SQH};
    const float s8[8] = {0.f, -SQH, -1.f, -SQH, 0.f,  SQH, 1.f,  SQH};

    const unsigned short* Yb = Y + (size_t)bc * 16 * YPX;

    // ---- phase 1: magnitudes for base pixels (full, duplicated per half) ----
    for (int t = tid; t < YPX; t += 256) {
        float Yr[8], Yi[8];
        #pragma unroll
        for (int l = 0; l < 8; ++l) {
            Yr[l] = bf2f(Yb[(l * 2 + 0) * YPX + t]);
            Yi[l] = bf2f(Yb[(l * 2 + 1) * YPX + t]);
        }
        #pragma unroll
        for (int tt = 0; tt < 8; ++tt) {
            float gr = 0.f, gi = 0.f;
            #pragma unroll
            for (int l = 0; l < 8; ++l) {
                const int k = (tt * l) & 7;
                gr += c8[k] * Yr[l] - s8[k] * Yi[l];
                gi += c8[k] * Yi[l] + s8[k] * Yr[l];
            }
            mgus[tt * YPX + t] = f2bf(sqrtf(gr * gr + gi * gi));
        }
    }
    __syncthreads();

    // ---- phase 2: coalesced x pass over this half's 1568 px ----
    float S[8], X[8];
    #pragma unroll
    for (int i = 0; i < 8; ++i) { S[i] = 0.f; X[i] = 0.f; }
    const size_t xbase = ((size_t)(b * 8) * 64 + c) * HW;   // + l*64*HW
    const int t0 = half * 1568, t1 = t0 + 1568;

    for (int t = t0 + tid; t < t1; t += 256) {
        int kh = t / 56, kw = t - kh * 56;
        bool flip = (kh > 28);
        int bt = flip ? ((56 - kh) * 56 + (kw ? 56 - kw : 0)) : t;
        #pragma unroll
        for (int l = 0; l < 8; ++l) {
            float xv = x[xbase + (size_t)l * 64 * HW + t];
            int sel = flip ? ((8 - l) & 7) : l;
            S[l] += bf2f(mgus[sel * YPX + bt]) * xv;
            X[l] += xv;
        }
    }

    #pragma unroll
    for (int i = 0; i < 8; ++i) {
        #pragma unroll
        for (int m = 1; m < 64; m <<= 1) {
            S[i] += __shfl_xor(S[i], m);
            X[i] += __shfl_xor(X[i], m);
        }
    }
    if (lane == 0) {
        #pragma unroll
        for (int i = 0; i < 8; ++i) { red[wv][i] = S[i]; red[wv][8 + i] = X[i]; }
    }
    __syncthreads();
    if (tid < 8) {
        float s = 0.f, xs = 0.f;
        #pragma unroll
        for (int w = 0; w < 4; ++w) { s += red[w][tid]; xs += red[w][8 + tid]; }
        const float kS = 0.01f / (56.0f * 2.8284271247461903f);
        float* dst = half ? poolB : poolA;
        dst[bc * 8 + tid] = (xs + kS * s) / 3136.0f;
    }
}

// ---------------------------------------------------------------------------
// Kernel 2: calib + fc (pooled = poolA + poolB, summed here — linear)
// ---------------------------------------------------------------------------
__global__ __launch_bounds__(64)
void calib_kernel(const float* __restrict__ poolA, const float* __restrict__ poolB,
                  const float* __restrict__ tw_, const float* __restrict__ tb,
                  const float* __restrict__ fcw, const float* __restrict__ fcb,
                  const float* __restrict__ convb,
                  float* __restrict__ scale, float* __restrict__ fbias) {
    const int nn = blockIdx.x;
    const int b = nn >> 3, l = nn & 7;
    const int o = threadIdx.x;
    const float* pA = poolA + b * 512 + l;
    const float* pB = poolB + b * 512 + l;
    float dot = 0.f;
    #pragma unroll 8
    for (int c0 = 0; c0 < 64; ++c0) dot += tw_[o * 64 + c0] * (pA[c0 * 8] + pB[c0 * 8]);
    float fcp = fcw[o] * (pA[o * 8] + pB[o * 8]);
    #pragma unroll
    for (int off = 32; off > 0; off >>= 1) fcp += __shfl_down(fcp, off);
    float fcout = __shfl(fcp, 0) + fcb[0];
    scale[nn * 64 + o] = 1.0f + tb[o] + dot;
    fbias[nn * 64 + o] = convb[o] * (fcout + 1.0f);
}

// ---------------------------------------------------------------------------
// Kernel 3: conv as bf16 MFMA GEMM. R12 core (pipelined 5x7 staging, lchash,
// 8-row aligned tiles) + XCD-aligned grid dim3(64,7): nn = blockIdx.x, so
// all 7 row-tiles of a frame run on XCD nn%8 (halo rows + frame x L2-shared;
// R9 evidence: FETCH 31.7 -> 25.6 MB).
// Residual recovered from LDS: xs holds bf16(x*scale[i]);
// residual = bf2f(xs)/scale[o] (saves 51 MB fetch).
// ---------------------------------------------------------------------------
__global__ __launch_bounds__(256, 2)
void conv_mfma_kernel(const float* __restrict__ x,
                      const unsigned short* __restrict__ Wp,
                      const float* __restrict__ scale, const float* __restrict__ fbias,
                      float* __restrict__ out,
                      float* __restrict__ psum, float* __restrict__ psum2) {
    const int nn = blockIdx.x;           // frame; XCD = nn%8
    const int rt = blockIdx.y;           // 0..6 row-tile
    const int tid  = threadIdx.x;
    const int lane = tid & 63;
    const int wv   = tid >> 6;
    const int r0   = rt * 8;

    __shared__ unsigned short xs[10 * 60 * 64];   // 76.8 KB
    __shared__ float fb[64], ssc[64], rsc[64], bn1[64], bn2[64];

    if (tid < 64) {
        fb[tid]  = fbias[nn * 64 + tid];
        float s  = scale[nn * 64 + tid];
        ssc[tid] = s;
        rsc[tid] = 1.0f / s;
        bn1[tid] = 0.f; bn2[tid] = 0.f;
    }
    __syncthreads();

    // main staging: 35 iters (8960 = 35*256), batched 5x7 (pipelined loads)
    #pragma unroll 1
    for (int bb = 0; bb < 5; ++bb) {
        float4 v[7];
        #pragma unroll
        for (int k = 0; k < 7; ++k) {
            int t = tid + (bb * 7 + k) * 256;
            int c4 = t % 14;
            int rr = (t / 14) % 10;
            int i  = t / 140;
            int gr = r0 - 1 + rr;
            v[k] = make_float4(0.f, 0.f, 0.f, 0.f);
            if (gr >= 0 && gr < 56)
                v[k] = *(const float4*)(x + ((size_t)(nn * 64 + i) * HW + gr * 56 + c4 * 4));
        }
        #pragma unroll
        for (int k = 0; k < 7; ++k) {
            int t = tid + (bb * 7 + k) * 256;
            int c4 = t % 14;
            int rr = (t / 14) % 10;
            int i  = t / 140;
            float s = ssc[i];
            int g = i >> 3, il = i & 7;
            float vv[4] = {v[k].x, v[k].y, v[k].z, v[k].w};
            #pragma unroll
            for (int j = 0; j < 4; ++j) {
                int lc = c4 * 4 + 1 + j;
                xs[(rr * 60 + lc) * 64 + (((g ^ lchash(lc)) << 3) | il)] = f2bf(vv[j] * s);
            }
        }
    }
    // zero cols 0 and 57: exactly 5 iters (1280 = 5*256)
    #pragma unroll
    for (int k = 0; k < 5; ++k) {
        int idx = tid + k * 256;                 // 0..1279 = 64i x 20
        int i   = idx / 20;
        int rem = idx - i * 20;
        int rr  = rem >> 1;
        int lc  = (rem & 1) * 57;
        int g = i >> 3, il = i & 7;
        xs[(rr * 60 + lc) * 64 + (((g ^ lchash(lc)) << 3) | il)] = 0;
    }
    __syncthreads();

    const int pxo = lane & 15;
    const int q   = lane >> 4;

    float4a acc[7][4];
    #pragma unroll
    for (int j = 0; j < 7; ++j)
        #pragma unroll
        for (int ot = 0; ot < 4; ++ot) acc[j][ot] = (float4a){0.f, 0.f, 0.f, 0.f};

    int rp[7], cp[7];
    #pragma unroll
    for (int j = 0; j < 7; ++j) {
        int px = (wv * 7 + j) * 16 + pxo;
        rp[j] = px / 56;
        cp[j] = px - rp[j] * 56;
    }

    #pragma unroll 1
    for (int kk = 0; kk < 9; ++kk) {
        const int dr = kk / 3, dc = kk - dr * 3;
        short8 a[4][2];
        #pragma unroll
        for (int ot = 0; ot < 4; ++ot)
            #pragma unroll
            for (int ih = 0; ih < 2; ++ih)
                a[ot][ih] = *(const short8*)(Wp + ((kk * 64 + ot * 16 + pxo) * 64 + ih * 32 + q * 8));

        #pragma unroll
        for (int j = 0; j < 7; ++j) {
            int lc = cp[j] + dc;
            int base = ((rp[j] + dr) * 60 + lc) * 64;
            int sw = lchash(lc);
            #pragma unroll
            for (int ih = 0; ih < 2; ++ih) {
                short8 bv = *(const short8*)&xs[base + (((q + ih * 4) ^ sw) << 3)];
                #pragma unroll
                for (int ot = 0; ot < 4; ++ot)
                    acc[j][ot] = __builtin_amdgcn_mfma_f32_16x16x32_bf16(a[ot][ih], bv, acc[j][ot], 0, 0, 0);
            }
        }
    }

    float bs[4][4], bs2[4][4];
    #pragma unroll
    for (int ot = 0; ot < 4; ++ot)
        #pragma unroll
        for (int r = 0; r < 4; ++r) { bs[ot][r] = 0.f; bs2[ot][r] = 0.f; }

    #pragma unroll
    for (int j = 0; j < 7; ++j) {
        int px  = (wv * 7 + j) * 16 + pxo;
        int gpx = r0 * 56 + px;
        int rr  = rp[j] + 1;
        int lc  = cp[j] + 1;
        int sw  = lchash(lc);
        int rowbase = (rr * 60 + lc) * 64;
        #pragma unroll
        for (int ot = 0; ot < 4; ++ot) {
            int g  = ot * 2 + (q >> 1);
            ushort4 uu = *(const ushort4*)(xs + rowbase + (((g ^ sw) << 3) | ((q & 1) * 4)));
            float resid[4] = {bf2f(uu.x), bf2f(uu.y), bf2f(uu.z), bf2f(uu.w)};
            #pragma unroll
            for (int r = 0; r < 4; ++r) {
                int o = ot * 16 + q * 4 + r;
                size_t off = (size_t)(nn * 64 + o) * HW + gpx;
                float v = acc[j][ot][r] + resid[r] * rsc[o] + fb[o];
                out[off] = v;
                bs[ot][r]  += v;
                bs2[ot][r] += v * v;
            }
        }
    }
    #pragma unroll
    for (int ot = 0; ot < 4; ++ot)
        #pragma unroll
        for (int r = 0; r < 4; ++r) {
            #pragma unroll
            for (int m = 1; m < 16; m <<= 1) {
                bs[ot][r]  += __shfl_xor(bs[ot][r], m);
                bs2[ot][r] += __shfl_xor(bs2[ot][r], m);
            }
        }
    if (pxo == 0) {
        #pragma unroll
        for (int ot = 0; ot < 4; ++ot)
            #pragma unroll
            for (int r = 0; r < 4; ++r) {
                int o = ot * 16 + q * 4 + r;
                atomicAdd(&bn1[o], bs[ot][r]);
                atomicAdd(&bn2[o], bs2[ot][r]);
            }
    }
    __syncthreads();
    if (tid < 64) {
        int bl = nn * 7 + rt;
        psum[bl * 64 + tid]  = bn1[tid];
        psum2[bl * 64 + tid] = bn2[tid];
    }
}

// ---------------------------------------------------------------------------
// Kernel 4: reduce partials -> per-channel mean / invstd
// ---------------------------------------------------------------------------
__global__ __launch_bounds__(256)
void bnstat_kernel(const float* __restrict__ psum, const float* __restrict__ psum2,
                   float* __restrict__ bn) {
    const int o = blockIdx.x;
    const int tid = threadIdx.x;
    float s = 0.f, s2 = 0.f;
    for (int bl = tid; bl < NBLK2; bl += 256) {
        s  += psum[bl * 64 + o];
        s2 += psum2[bl * 64 + o];
    }
    __shared__ float r1[256], r2[256];
    r1[tid] = s; r2[tid] = s2;
    __syncthreads();
    for (int st = 128; st > 0; st >>= 1) {
        if (tid < st) { r1[tid] += r1[tid + st]; r2[tid] += r2[tid + st]; }
        __syncthreads();
    }
    if (tid == 0) {
        const float N = 64.0f * (float)HW;
        float mean = r1[0] / N;
        float var  = r2[0] / N - mean * mean;
        bn[o]      = mean;
        bn[64 + o] = rsqrtf(var + 1e-5f);
    }
}

// ---------------------------------------------------------------------------
// Kernel 5: BN + SiLU in place — float4 grid-stride (G13), 2048 blocks.
// HW/4 = 784, so a float4 never crosses a channel plane.
// ---------------------------------------------------------------------------
__global__ __launch_bounds__(256)
void bnsilu_kernel(float* __restrict__ out, const float* __restrict__ bn,
                   const float* __restrict__ gamma, const float* __restrict__ beta) {
    const int total4 = NF * 64 * HW / 4;             // 3,211,264
    for (int i4 = blockIdx.x * 256 + threadIdx.x; i4 < total4; i4 += 2048 * 256) {
        int c = (i4 / 784) & 63;
        float mean = bn[c], is = bn[64 + c], g = gamma[c], bt = beta[c];
        float4 v = ((const float4*)out)[i4];
        float yy[4] = {v.x, v.y, v.z, v.w};
        #pragma unroll
        for (int k = 0; k < 4; ++k) {
            float y = (yy[k] - mean) * is * g + bt;
            yy[k] = y / (1.0f + expf(-y));
        }
        ((float4*)out)[i4] = make_float4(yy[0], yy[1], yy[2], yy[3]);
    }
}

extern "C" void kernel_launch(void* const* d_in, const int* in_sizes, int n_in,
                              void* d_out, int out_size, void* d_ws, size_t ws_size,
                              hipStream_t stream) {
    const float* x          = (const float*)d_in[0];
    const float* temporal_w = (const float*)d_in[1];
    const float* temporal_b = (const float*)d_in[2];
    const float* fc_w       = (const float*)d_in[3];
    const float* fc_b       = (const float*)d_in[4];
    const float* conv_w     = (const float*)d_in[5];
    const float* conv_b     = (const float*)d_in[6];
    const float* bn_gamma   = (const float*)d_in[7];
    const float* bn_beta    = (const float*)d_in[8];
    float* out = (float*)d_out;
    float* ws  = (float*)d_ws;

    float* poolA  = ws;                               // 4096 f
    float* poolB  = ws + 4096;                        // 4096 f
    float* scale  = ws + 8192;                        // 4096 f
    float* fbias  = ws + 12288;                       // 4096 f
    unsigned short* Wp = (unsigned short*)(ws + 16384);   // 36864 us = 18432 f
    float* psum   = ws + 16384 + 18432;               // 448*64 f
    float* psum2  = psum + NBLK2 * 64;                // 448*64 f
    float* bn     = psum2 + NBLK2 * 64;               // 128 f
    unsigned short* Ffix = (unsigned short*)(bn + 128);   // 16384 us
    unsigned short* Fs1  = Ffix + 16384;              // 4096 us

    // Y scratch (26.6 MB bf16) lives in `out` (51.4 MB), dead until conv.
    unsigned short* Y = (unsigned short*)out;

    pack_kernel<<<224, 256, 0, stream>>>(conv_w, Ffix, Wp, Fs1);
    dft2d_kernel<<<4096, 256, 0, stream>>>(x, Fs1, Ffix, Y);
    combine_kernel<<<1024, 256, 0, stream>>>(x, Y, poolA, poolB);
    calib_kernel<<<64, 64, 0, stream>>>(poolA, poolB, temporal_w, temporal_b,
                                        fc_w, fc_b, conv_b, scale, fbias);
    conv_mfma_kernel<<<dim3(64, 7), 256, 0, stream>>>(x, Wp, scale, fbias,
                                                      out, psum, psum2);
    bnstat_kernel<<<64, 256, 0, stream>>>(psum, psum2, bn);
    bnsilu_kernel<<<2048, 256, 0, stream>>>(out, bn, bn_gamma, bn_beta);
}

// Round 15
// 208.498 us; speedup vs baseline: 1.0208x; 1.0208x over previous
//
#include <hip/hip_runtime.h>
#include <cmath>

#define HW 3136          // 56*56
#define NF 64            // BB*LL frames
#define NBLK2 448        // NF * 7 row-tiles (conv blocks, 8 rows each)
#define YROWS 29         // Hermitian: rows 0..28 of spatial DFT stored
#define YPX 1624         // 29*56

typedef __attribute__((ext_vector_type(8))) short short8;
typedef __attribute__((ext_vector_type(4))) float float4a;

__device__ __forceinline__ unsigned short f2bf(float f) {
    unsigned int u = __float_as_uint(f);
    u += 0x7fffu + ((u >> 16) & 1u);   // RNE
    return (unsigned short)(u >> 16);
}
__device__ __forceinline__ float bf2f(unsigned short u) {
    return __uint_as_float(((unsigned int)u) << 16);
}
// LDS channel-group hash: spreads both read-side (consecutive lc) and
// write-side (stride-4 lc) accesses across all 8 16B slots.
__device__ __forceinline__ int lchash(int lc) {
    return (lc ^ (lc >> 2)) & 7;
}

// ---------------------------------------------------------------------------
// Kernel 0: pack DFT matrices + repack conv_w.
//  blocks 0..63   : Ffix (stage-2 B operand), k-slots interleaved:
//                   slot 2h = col-Re, 2h+1 = col-Im.
//                   p=0 -> [Fr | -Fi], p=1 -> [Fi | Fr].
//  blocks 64..207 : Wp[kk][o][i] bf16 from conv_w[o][i][kk].
//  blocks 208..223: Fs1 (stage-1 A operand): M-stack rows 0..28 = Fr rows,
//                   rows 32..60 = Fi rows, pads zero. K = 0..55 pad 64.
// ---------------------------------------------------------------------------
__global__ __launch_bounds__(256)
void pack_kernel(const float* __restrict__ cw,
                 unsigned short* __restrict__ Ffix,
                 unsigned short* __restrict__ Wp,
                 unsigned short* __restrict__ Fs1) {
    if (blockIdx.x < 64) {
        int idx = blockIdx.x * 256 + threadIdx.x;    // 16384
        int j    = idx & 7;
        int lane = (idx >> 3) & 63;
        int ks   = (idx >> 9) & 3;
        int t    = (idx >> 11) & 3;
        int p    = (idx >> 13) & 1;
        int mn = t * 16 + (lane & 15);
        int k  = ks * 32 + (lane >> 4) * 8 + j;      // interleaved slot
        float val = 0.f;
        if (mn < 56 && k < 112) {
            int h = k >> 1;
            int prod = (mn * h) % 56;
            float ang = -6.2831853071795864f * (float)prod / 56.0f;
            float cr = cosf(ang);                    // Fr
            float ci = sinf(ang);                    // Fi
            if (p == 0) val = (k & 1) ? -ci : cr;    // [Fr | -Fi]
            else        val = (k & 1) ?  cr : ci;    // [Fi |  Fr]
        }
        Ffix[idx] = f2bf(val);
    } else if (blockIdx.x < 208) {
        int idx = (blockIdx.x - 64) * 256 + threadIdx.x;
        if (idx < 36864) {
            int i  = idx & 63;
            int o  = (idx >> 6) & 63;
            int kk = idx >> 12;
            Wp[idx] = f2bf(cw[(o * 64 + i) * 9 + kk]);
        }
    } else {
        int idx = (blockIdx.x - 208) * 256 + threadIdx.x;  // 4096
        int j  = idx & 7;
        int ln = (idx >> 3) & 63;
        int ks = (idx >> 9) & 1;
        int mt = (idx >> 10) & 3;
        int m = mt * 16 + (ln & 15);
        int k = ks * 32 + (ln >> 4) * 8 + j;
        float val = 0.f;
        if (k < 56) {
            if (m < 29) {                            // Fr row m
                int prod = (m * k) % 56;
                val = cosf(-6.2831853071795864f * (float)prod / 56.0f);
            } else if (m >= 32 && m < 61) {          // Fi row m-32
                int mm = m - 32;
                int prod = (mm * k) % 56;
                val = sinf(-6.2831853071795864f * (float)prod / 56.0f);
            }
        }
        Fs1[idx] = f2bf(val);
    }
}

// ---------------------------------------------------------------------------
// Kernel 1a: per-plane spatial 2D DFT (rows 0..28 via Hermitian symmetry).
// R12 decode (l = bid&7): the 8 l-planes read DISJOINT x planes (no sharing
// to exploit), and adjacent launch order keeps Y writes streaming.
// ---------------------------------------------------------------------------
__global__ __launch_bounds__(256)
void dft2d_kernel(const float* __restrict__ x,
                  const unsigned short* __restrict__ Fs1,
                  const unsigned short* __restrict__ Ffix,
                  unsigned short* __restrict__ Y) {
    const int bid = blockIdx.x;          // (b*64+c)*8 + l
    const int l  = bid & 7;
    const int bc = bid >> 3;
    const int c  = bc & 63;
    const int b  = bc >> 6;
    const int tid  = threadIdx.x;
    const int lane = tid & 63;
    const int wv   = tid >> 6;           // 0..3
    const int n    = lane & 15;
    const int q    = lane >> 4;

    __shared__ unsigned short xT[64 * 68];   // [w][h] stride 68, 8704 B
    __shared__ unsigned short P[32 * 136];   // [r][slot] stride 136, 8704 B

    // zero ONLY xT pad regions (disjoint from staged area)
    for (int t = tid; t < 656; t += 256) {
        if (t < 384) ((unsigned int*)xT)[(t / 6) * 34 + 28 + (t % 6)] = 0u;
        else         ((unsigned int*)xT)[56 * 34 + (t - 384)] = 0u;
    }
    // stage x plane -> xT (transposed, bf16)
    const float* xp = x + ((size_t)((b * 8 + l) * 64 + c)) * HW;
    for (int t = tid; t < 784; t += 256) {
        int h = t / 14, w4 = t - h * 14;
        float4 v = *(const float4*)(xp + h * 56 + w4 * 4);
        xT[(w4 * 4 + 0) * 68 + h] = f2bf(v.x);
        xT[(w4 * 4 + 1) * 68 + h] = f2bf(v.y);
        xT[(w4 * 4 + 2) * 68 + h] = f2bf(v.z);
        xT[(w4 * 4 + 3) * 68 + h] = f2bf(v.w);
    }
    __syncthreads();

    // ---- stage 1: wave wv owns m-tile wv. out P[m][w], K = h (56 pad 64) ----
    {
        float4a acc[4];
        #pragma unroll
        for (int nt = 0; nt < 4; ++nt) acc[nt] = (float4a){0.f, 0.f, 0.f, 0.f};
        #pragma unroll
        for (int ks = 0; ks < 2; ++ks) {
            short8 afr = *(const short8*)(Fs1 + ((size_t)((wv * 2 + ks) * 64 + lane)) * 8);
            #pragma unroll
            for (int nt = 0; nt < 4; ++nt) {
                short8 bfr = *(const short8*)(xT + (nt * 16 + n) * 68 + ks * 32 + q * 8);
                acc[nt] = __builtin_amdgcn_mfma_f32_16x16x32_bf16(afr, bfr, acc[nt], 0, 0, 0);
            }
        }
        #pragma unroll
        for (int nt = 0; nt < 4; ++nt)
            #pragma unroll
            for (int r = 0; r < 4; ++r) {
                int m = wv * 16 + q * 4 + r;
                P[(m & 31) * 136 + 2 * (nt * 16 + n) + (m >> 5)] = f2bf(acc[nt][r]);
            }
    }
    __syncthreads();

    // ---- stage 2: wave wv: p = wv>>1 (re/im), ch = wv&1 (col half) ----
    {
        const int p  = wv >> 1;
        const int ch = wv & 1;
        short8 afr[2][4];
        #pragma unroll
        for (int mt = 0; mt < 2; ++mt)
            #pragma unroll
            for (int ks = 0; ks < 4; ++ks)
                afr[mt][ks] = *(const short8*)(P + (mt * 16 + n) * 136 + ks * 32 + q * 8);
        float4a acc[2][2];
        #pragma unroll
        for (int mt = 0; mt < 2; ++mt)
            #pragma unroll
            for (int u = 0; u < 2; ++u) acc[mt][u] = (float4a){0.f, 0.f, 0.f, 0.f};
        #pragma unroll
        for (int ks = 0; ks < 4; ++ks)
            #pragma unroll
            for (int u = 0; u < 2; ++u) {
                int nt = ch * 2 + u;
                short8 bfr = *(const short8*)(Ffix + ((size_t)(((p * 4 + nt) * 4 + ks) * 64 + lane)) * 8);
                #pragma unroll
                for (int mt = 0; mt < 2; ++mt)
                    acc[mt][u] = __builtin_amdgcn_mfma_f32_16x16x32_bf16(afr[mt][ks], bfr, acc[mt][u], 0, 0, 0);
            }
        unsigned short* Yo = Y + ((size_t)bid * 2 + p) * YPX;
        #pragma unroll
        for (int mt = 0; mt < 2; ++mt)
            #pragma unroll
            for (int u = 0; u < 2; ++u)
                #pragma unroll
                for (int r = 0; r < 4; ++r) {
                    int row = mt * 16 + q * 4 + r;
                    int col = (ch * 2 + u) * 16 + n;
                    if (row < YROWS && col < 56)
                        Yo[row * 56 + col] = f2bf(acc[mt][u][r]);
                }
    }
}

// ---------------------------------------------------------------------------
// Kernel 1b: temporal combine + magnitude + weighted pooling.
// Split 2x per (b,c) with ADJACENT halves (half = bid&1): both halves run
// concurrently on the same wavefront of blocks so Y[bc] is read once into
// L2 and shared (R14's separated decode cost ~4 us in Y re-fetch).
// mg stored bf16 (26 KB LDS), 4 blocks/CU.
// ---------------------------------------------------------------------------
__global__ __launch_bounds__(256)
void combine_kernel(const float* __restrict__ x,
                    const unsigned short* __restrict__ Y,
                    float* __restrict__ poolA, float* __restrict__ poolB) {
    const int bid = blockIdx.x;          // bc*2 + half
    const int half = bid & 1;
    const int bc = bid >> 1;             // b*64 + c
    const int c  = bc & 63;
    const int b  = bc >> 6;
    const int tid  = threadIdx.x;
    const int lane = tid & 63;
    const int wv   = tid >> 6;

    __shared__ unsigned short mgus[8 * YPX];   // 25984 B (bf16 magnitudes)
    __shared__ float red[4][16];

    const float SQH = 0.70710678118654752f;
    // w8[k] = e^{-2*pi*i*k/8}: cr = cos, ci = -sin
    const float c8[8] = {1.f,  SQH, 0.f, -SQH, -1.f, -SQH, 0.f,  SQH};
    const float s8[8] = {0.f, -SQH, -1.f, -SQH, 0.f,  SQH, 1.f,  SQH};

    const unsigned short* Yb = Y + (size_t)bc * 16 * YPX;

    // ---- phase 1: magnitudes for base pixels (full, duplicated per half) ----
    for (int t = tid; t < YPX; t += 256) {
        float Yr[8], Yi[8];
        #pragma unroll
        for (int l = 0; l < 8; ++l) {
            Yr[l] = bf2f(Yb[(l * 2 + 0) * YPX + t]);
            Yi[l] = bf2f(Yb[(l * 2 + 1) * YPX + t]);
        }
        #pragma unroll
        for (int tt = 0; tt < 8; ++tt) {
            float gr = 0.f, gi = 0.f;
            #pragma unroll
            for (int l = 0; l < 8; ++l) {
                const int k = (tt * l) & 7;
                gr += c8[k] * Yr[l] - s8[k] * Yi[l];
                gi += c8[k] * Yi[l] + s8[k] * Yr[l];
            }
            mgus[tt * YPX + t] = f2bf(sqrtf(gr * gr + gi * gi));
        }
    }
    __syncthreads();

    // ---- phase 2: coalesced x pass over this half's 1568 px ----
    float S[8], X[8];
    #pragma unroll
    for (int i = 0; i < 8; ++i) { S[i] = 0.f; X[i] = 0.f; }
    const size_t xbase = ((size_t)(b * 8) * 64 + c) * HW;   // + l*64*HW
    const int t0 = half * 1568, t1 = t0 + 1568;

    for (int t = t0 + tid; t < t1; t += 256) {
        int kh = t / 56, kw = t - kh * 56;
        bool flip = (kh > 28);
        int bt = flip ? ((56 - kh) * 56 + (kw ? 56 - kw : 0)) : t;
        #pragma unroll
        for (int l = 0; l < 8; ++l) {
            float xv = x[xbase + (size_t)l * 64 * HW + t];
            int sel = flip ? ((8 - l) & 7) : l;
            S[l] += bf2f(mgus[sel * YPX + bt]) * xv;
            X[l] += xv;
        }
    }

    #pragma unroll
    for (int i = 0; i < 8; ++i) {
        #pragma unroll
        for (int m = 1; m < 64; m <<= 1) {
            S[i] += __shfl_xor(S[i], m);
            X[i] += __shfl_xor(X[i], m);
        }
    }
    if (lane == 0) {
        #pragma unroll
        for (int i = 0; i < 8; ++i) { red[wv][i] = S[i]; red[wv][8 + i] = X[i]; }
    }
    __syncthreads();
    if (tid < 8) {
        float s = 0.f, xs = 0.f;
        #pragma unroll
        for (int w = 0; w < 4; ++w) { s += red[w][tid]; xs += red[w][8 + tid]; }
        const float kS = 0.01f / (56.0f * 2.8284271247461903f);
        float* dst = half ? poolB : poolA;
        dst[bc * 8 + tid] = (xs + kS * s) / 3136.0f;
    }
}

// ---------------------------------------------------------------------------
// Kernel 2: calib + fc (pooled = poolA + poolB, summed here — linear)
// ---------------------------------------------------------------------------
__global__ __launch_bounds__(64)
void calib_kernel(const float* __restrict__ poolA, const float* __restrict__ poolB,
                  const float* __restrict__ tw_, const float* __restrict__ tb,
                  const float* __restrict__ fcw, const float* __restrict__ fcb,
                  const float* __restrict__ convb,
                  float* __restrict__ scale, float* __restrict__ fbias) {
    const int nn = blockIdx.x;
    const int b = nn >> 3, l = nn & 7;
    const int o = threadIdx.x;
    const float* pA = poolA + b * 512 + l;
    const float* pB = poolB + b * 512 + l;
    float dot = 0.f;
    #pragma unroll 8
    for (int c0 = 0; c0 < 64; ++c0) dot += tw_[o * 64 + c0] * (pA[c0 * 8] + pB[c0 * 8]);
    float fcp = fcw[o] * (pA[o * 8] + pB[o * 8]);
    #pragma unroll
    for (int off = 32; off > 0; off >>= 1) fcp += __shfl_down(fcp, off);
    float fcout = __shfl(fcp, 0) + fcb[0];
    scale[nn * 64 + o] = 1.0f + tb[o] + dot;
    fbias[nn * 64 + o] = convb[o] * (fcout + 1.0f);
}

// ---------------------------------------------------------------------------
// Kernel 3: conv as bf16 MFMA GEMM. R12 core (pipelined 5x7 staging, lchash,
// 8-row aligned tiles) + XCD-aligned grid dim3(64,7) (kept from R14:
// FETCH 31.8 -> 25.5 MB verified, dur-neutral, aligned writes intact).
// Residual recovered from LDS: xs holds bf16(x*scale[i]);
// residual = bf2f(xs)/scale[o] (saves 51 MB fetch).
// ---------------------------------------------------------------------------
__global__ __launch_bounds__(256, 2)
void conv_mfma_kernel(const float* __restrict__ x,
                      const unsigned short* __restrict__ Wp,
                      const float* __restrict__ scale, const float* __restrict__ fbias,
                      float* __restrict__ out,
                      float* __restrict__ psum, float* __restrict__ psum2) {
    const int nn = blockIdx.x;           // frame; XCD = nn%8
    const int rt = blockIdx.y;           // 0..6 row-tile
    const int tid  = threadIdx.x;
    const int lane = tid & 63;
    const int wv   = tid >> 6;
    const int r0   = rt * 8;

    __shared__ unsigned short xs[10 * 60 * 64];   // 76.8 KB
    __shared__ float fb[64], ssc[64], rsc[64], bn1[64], bn2[64];

    if (tid < 64) {
        fb[tid]  = fbias[nn * 64 + tid];
        float s  = scale[nn * 64 + tid];
        ssc[tid] = s;
        rsc[tid] = 1.0f / s;
        bn1[tid] = 0.f; bn2[tid] = 0.f;
    }
    __syncthreads();

    // main staging: 35 iters (8960 = 35*256), batched 5x7 (pipelined loads)
    #pragma unroll 1
    for (int bb = 0; bb < 5; ++bb) {
        float4 v[7];
        #pragma unroll
        for (int k = 0; k < 7; ++k) {
            int t = tid + (bb * 7 + k) * 256;
            int c4 = t % 14;
            int rr = (t / 14) % 10;
            int i  = t / 140;
            int gr = r0 - 1 + rr;
            v[k] = make_float4(0.f, 0.f, 0.f, 0.f);
            if (gr >= 0 && gr < 56)
                v[k] = *(const float4*)(x + ((size_t)(nn * 64 + i) * HW + gr * 56 + c4 * 4));
        }
        #pragma unroll
        for (int k = 0; k < 7; ++k) {
            int t = tid + (bb * 7 + k) * 256;
            int c4 = t % 14;
            int rr = (t / 14) % 10;
            int i  = t / 140;
            float s = ssc[i];
            int g = i >> 3, il = i & 7;
            float vv[4] = {v[k].x, v[k].y, v[k].z, v[k].w};
            #pragma unroll
            for (int j = 0; j < 4; ++j) {
                int lc = c4 * 4 + 1 + j;
                xs[(rr * 60 + lc) * 64 + (((g ^ lchash(lc)) << 3) | il)] = f2bf(vv[j] * s);
            }
        }
    }
    // zero cols 0 and 57: exactly 5 iters (1280 = 5*256)
    #pragma unroll
    for (int k = 0; k < 5; ++k) {
        int idx = tid + k * 256;                 // 0..1279 = 64i x 20
        int i   = idx / 20;
        int rem = idx - i * 20;
        int rr  = rem >> 1;
        int lc  = (rem & 1) * 57;
        int g = i >> 3, il = i & 7;
        xs[(rr * 60 + lc) * 64 + (((g ^ lchash(lc)) << 3) | il)] = 0;
    }
    __syncthreads();

    const int pxo = lane & 15;
    const int q   = lane >> 4;

    float4a acc[7][4];
    #pragma unroll
    for (int j = 0; j < 7; ++j)
        #pragma unroll
        for (int ot = 0; ot < 4; ++ot) acc[j][ot] = (float4a){0.f, 0.f, 0.f, 0.f};

    int rp[7], cp[7];
    #pragma unroll
    for (int j = 0; j < 7; ++j) {
        int px = (wv * 7 + j) * 16 + pxo;
        rp[j] = px / 56;
        cp[j] = px - rp[j] * 56;
    }

    #pragma unroll 1
    for (int kk = 0; kk < 9; ++kk) {
        const int dr = kk / 3, dc = kk - dr * 3;
        short8 a[4][2];
        #pragma unroll
        for (int ot = 0; ot < 4; ++ot)
            #pragma unroll
            for (int ih = 0; ih < 2; ++ih)
                a[ot][ih] = *(const short8*)(Wp + ((kk * 64 + ot * 16 + pxo) * 64 + ih * 32 + q * 8));

        #pragma unroll
        for (int j = 0; j < 7; ++j) {
            int lc = cp[j] + dc;
            int base = ((rp[j] + dr) * 60 + lc) * 64;
            int sw = lchash(lc);
            #pragma unroll
            for (int ih = 0; ih < 2; ++ih) {
                short8 bv = *(const short8*)&xs[base + (((q + ih * 4) ^ sw) << 3)];
                #pragma unroll
                for (int ot = 0; ot < 4; ++ot)
                    acc[j][ot] = __builtin_amdgcn_mfma_f32_16x16x32_bf16(a[ot][ih], bv, acc[j][ot], 0, 0, 0);
            }
        }
    }

    float bs[4][4], bs2[4][4];
    #pragma unroll
    for (int ot = 0; ot < 4; ++ot)
        #pragma unroll
        for (int r = 0; r < 4; ++r) { bs[ot][r] = 0.f; bs2[ot][r] = 0.f; }

    #pragma unroll
    for (int j = 0; j < 7; ++j) {
        int px  = (wv * 7 + j) * 16 + pxo;
        int gpx = r0 * 56 + px;
        int rr  = rp[j] + 1;
        int lc  = cp[j] + 1;
        int sw  = lchash(lc);
        int rowbase = (rr * 60 + lc) * 64;
        #pragma unroll
        for (int ot = 0; ot < 4; ++ot) {
            int g  = ot * 2 + (q >> 1);
            ushort4 uu = *(const ushort4*)(xs + rowbase + (((g ^ sw) << 3) | ((q & 1) * 4)));
            float resid[4] = {bf2f(uu.x), bf2f(uu.y), bf2f(uu.z), bf2f(uu.w)};
            #pragma unroll
            for (int r = 0; r < 4; ++r) {
                int o = ot * 16 + q * 4 + r;
                size_t off = (size_t)(nn * 64 + o) * HW + gpx;
                float v = acc[j][ot][r] + resid[r] * rsc[o] + fb[o];
                out[off] = v;
                bs[ot][r]  += v;
                bs2[ot][r] += v * v;
            }
        }
    }
    #pragma unroll
    for (int ot = 0; ot < 4; ++ot)
        #pragma unroll
        for (int r = 0; r < 4; ++r) {
            #pragma unroll
            for (int m = 1; m < 16; m <<= 1) {
                bs[ot][r]  += __shfl_xor(bs[ot][r], m);
                bs2[ot][r] += __shfl_xor(bs2[ot][r], m);
            }
        }
    if (pxo == 0) {
        #pragma unroll
        for (int ot = 0; ot < 4; ++ot)
            #pragma unroll
            for (int r = 0; r < 4; ++r) {
                int o = ot * 16 + q * 4 + r;
                atomicAdd(&bn1[o], bs[ot][r]);
                atomicAdd(&bn2[o], bs2[ot][r]);
            }
    }
    __syncthreads();
    if (tid < 64) {
        int bl = nn * 7 + rt;
        psum[bl * 64 + tid]  = bn1[tid];
        psum2[bl * 64 + tid] = bn2[tid];
    }
}

// ---------------------------------------------------------------------------
// Kernel 4: reduce partials -> per-channel mean / invstd
// ---------------------------------------------------------------------------
__global__ __launch_bounds__(256)
void bnstat_kernel(const float* __restrict__ psum, const float* __restrict__ psum2,
                   float* __restrict__ bn) {
    const int o = blockIdx.x;
    const int tid = threadIdx.x;
    float s = 0.f, s2 = 0.f;
    for (int bl = tid; bl < NBLK2; bl += 256) {
        s  += psum[bl * 64 + o];
        s2 += psum2[bl * 64 + o];
    }
    __shared__ float r1[256], r2[256];
    r1[tid] = s; r2[tid] = s2;
    __syncthreads();
    for (int st = 128; st > 0; st >>= 1) {
        if (tid < st) { r1[tid] += r1[tid + st]; r2[tid] += r2[tid + st]; }
        __syncthreads();
    }
    if (tid == 0) {
        const float N = 64.0f * (float)HW;
        float mean = r1[0] / N;
        float var  = r2[0] / N - mean * mean;
        bn[o]      = mean;
        bn[64 + o] = rsqrtf(var + 1e-5f);
    }
}

// ---------------------------------------------------------------------------
// Kernel 5: BN + SiLU in place — float4 grid-stride (G13), 2048 blocks.
// HW/4 = 784, so a float4 never crosses a channel plane.
// ---------------------------------------------------------------------------
__global__ __launch_bounds__(256)
void bnsilu_kernel(float* __restrict__ out, const float* __restrict__ bn,
                   const float* __restrict__ gamma, const float* __restrict__ beta) {
    const int total4 = NF * 64 * HW / 4;             // 3,211,264
    for (int i4 = blockIdx.x * 256 + threadIdx.x; i4 < total4; i4 += 2048 * 256) {
        int c = (i4 / 784) & 63;
        float mean = bn[c], is = bn[64 + c], g = gamma[c], bt = beta[c];
        float4 v = ((const float4*)out)[i4];
        float yy[4] = {v.x, v.y, v.z, v.w};
        #pragma unroll
        for (int k = 0; k < 4; ++k) {
            float y = (yy[k] - mean) * is * g + bt;
            yy[k] = y / (1.0f + expf(-y));
        }
        ((float4*)out)[i4] = make_float4(yy[0], yy[1], yy[2], yy[3]);
    }
}

extern "C" void kernel_launch(void* const* d_in, const int* in_sizes, int n_in,
                              void* d_out, int out_size, void* d_ws, size_t ws_size,
                              hipStream_t stream) {
    const float* x          = (const float*)d_in[0];
    const float* temporal_w = (const float*)d_in[1];
    const float* temporal_b = (const float*)d_in[2];
    const float* fc_w       = (const float*)d_in[3];
    const float* fc_b       = (const float*)d_in[4];
    const float* conv_w     = (const float*)d_in[5];
    const float* conv_b     = (const float*)d_in[6];
    const float* bn_gamma   = (const float*)d_in[7];
    const float* bn_beta    = (const float*)d_in[8];
    float* out = (float*)d_out;
    float* ws  = (float*)d_ws;

    float* poolA  = ws;                               // 4096 f
    float* poolB  = ws + 4096;                        // 4096 f
    float* scale  = ws + 8192;                        // 4096 f
    float* fbias  = ws + 12288;                       // 4096 f
    unsigned short* Wp = (unsigned short*)(ws + 16384);   // 36864 us = 18432 f
    float* psum   = ws + 16384 + 18432;               // 448*64 f
    float* psum2  = psum + NBLK2 * 64;                // 448*64 f
    float* bn     = psum2 + NBLK2 * 64;               // 128 f
    unsigned short* Ffix = (unsigned short*)(bn + 128);   // 16384 us
    unsigned short* Fs1  = Ffix + 16384;              // 4096 us

    // Y scratch (26.6 MB bf16) lives in `out` (51.4 MB), dead until conv.
    unsigned short* Y = (unsigned short*)out;

    pack_kernel<<<224, 256, 0, stream>>>(conv_w, Ffix, Wp, Fs1);
    dft2d_kernel<<<4096, 256, 0, stream>>>(x, Fs1, Ffix, Y);
    combine_kernel<<<1024, 256, 0, stream>>>(x, Y, poolA, poolB);
    calib_kernel<<<64, 64, 0, stream>>>(poolA, poolB, temporal_w, temporal_b,
                                        fc_w, fc_b, conv_b, scale, fbias);
    conv_mfma_kernel<<<dim3(64, 7), 256, 0, stream>>>(x, Wp, scale, fbias,
                                                      out, psum, psum2);
    bnstat_kernel<<<64, 256, 0, stream>>>(psum, psum2, bn);
    bnsilu_kernel<<<2048, 256, 0, stream>>>(out, bn, bn_gamma, bn_beta);
}